// Round 1
// baseline (460.211 us; speedup 1.0000x reference)
//
#include <hip/hip_runtime.h>

// Problem constants (fixed shapes from the reference file)
#define BB 32
#define SS 1024
#define HH 384
#define MAXLEN 8192
#define H4 (HH / 4)                 // 96 float4 per row
#define OUT0 (BB * MAXLEN * HH)     // 100663296 floats: the expanded output
#define MEL_OFF OUT0                // 32 floats: mel_len
#define MASK_OFF (OUT0 + BB)        // 262144 floats: mel_mask

// One block per batch: scan durations -> cum in LDS, emit mel_len (as f32),
// searchsorted idx for every frame t (-1 if t >= mel_len), and the mask floats.
__global__ __launch_bounds__(1024) void k_prep(
    const int* __restrict__ dur,
    const unsigned char* __restrict__ mel_mask_in,
    float* __restrict__ out,
    int* __restrict__ idxbuf)
{
    __shared__ int cum[SS];
    const int b = blockIdx.x;
    const int tid = threadIdx.x;

    cum[tid] = dur[b * SS + tid];
    // Hillis-Steele inclusive scan, in place, read/write separated by barriers
    for (int off = 1; off < SS; off <<= 1) {
        __syncthreads();
        int v = (tid >= off) ? cum[tid - off] : 0;
        __syncthreads();
        cum[tid] += v;
    }
    __syncthreads();

    const int mel_len = cum[SS - 1];
    if (tid == 0) out[MEL_OFF + b] = (float)mel_len;

    // 8 frames per thread, coalesced stride-1024
    for (int k = 0; k < MAXLEN / SS; ++k) {
        const int t = tid + k * SS;
        // searchsorted(cum, t, side='right'): first j with cum[j] > t
        int lo = 0, hi = SS;
        while (lo < hi) {
            int mid = (lo + hi) >> 1;
            if (cum[mid] <= t) lo = mid + 1; else hi = mid;
        }
        int idx = (lo < SS) ? lo : (SS - 1);
        idxbuf[b * MAXLEN + t] = (t < mel_len) ? idx : -1;
        out[MASK_OFF + b * MAXLEN + t] = mel_mask_in[b * MAXLEN + t] ? 1.0f : 0.0f;
    }
}

// Flat float4 expansion: item i -> (frame ft, chunk c); gather x[b, idx[ft], :]
__global__ __launch_bounds__(256) void k_expand(
    const float4* __restrict__ x4,
    const int* __restrict__ idxbuf,
    float4* __restrict__ out4)
{
    const int i = blockIdx.x * 256 + threadIdx.x;   // < BB*MAXLEN*H4 = 25165824
    const int ft = i / H4;                          // global frame index b*8192+t
    const int c  = i - ft * H4;
    const int id = idxbuf[ft];
    float4 v = make_float4(0.f, 0.f, 0.f, 0.f);
    if (id >= 0) {
        const int b = ft >> 13;
        v = x4[(size_t)(b * SS + id) * H4 + c];
    }
    out4[i] = v;
}

extern "C" void kernel_launch(void* const* d_in, const int* in_sizes, int n_in,
                              void* d_out, int out_size, void* d_ws, size_t ws_size,
                              hipStream_t stream) {
    // setup_inputs order: x, src_mask, mel_mask, duration_target, pitch_target, max_len
    const float* x = (const float*)d_in[0];
    const unsigned char* mel_mask_in = (const unsigned char*)d_in[2];
    const int* dur = (const int*)d_in[3];
    float* out = (float*)d_out;
    int* idxbuf = (int*)d_ws;   // BB*MAXLEN ints = 1 MB

    k_prep<<<BB, 1024, 0, stream>>>(dur, mel_mask_in, out, idxbuf);

    const int n4 = BB * MAXLEN * H4;                // 25,165,824
    k_expand<<<n4 / 256, 256, 0, stream>>>((const float4*)x, idxbuf, (float4*)out);
}

// Round 3
// 446.611 us; speedup vs baseline: 1.0305x; 1.0305x over previous
//
#include <hip/hip_runtime.h>

// Problem constants (fixed shapes from the reference file)
#define BB 32
#define SS 1024
#define HH 384
#define MAXLEN 8192
#define H4 (HH / 4)                 // 96 float4 per row
#define OUT0 (BB * MAXLEN * HH)     // 100663296 floats: the expanded output
#define MEL_OFF OUT0                // 32 floats: mel_len (as f32)
#define MASK_OFF (OUT0 + BB)        // 262144 floats: mel_mask

// Native 16B vector type: __builtin_nontemporal_store rejects HIP's float4
// (struct-wrapped), but accepts clang ext_vector_type.
typedef float vfloat4 __attribute__((ext_vector_type(4)));

// One block per batch: inclusive scan of durations in LDS, emit mel_len (f32),
// searchsorted idx per frame (-1 when t >= mel_len), and mask floats.
// NOTE: bool inputs arrive widened to int32 (absmax==1.0 in R1 proved the
// byte-wise read was wrong) -> read mel_mask as const int*.
__global__ __launch_bounds__(1024) void k_prep(
    const int* __restrict__ dur,
    const int* __restrict__ mel_mask_in,
    float* __restrict__ out,
    int* __restrict__ idxbuf)
{
    __shared__ int cum[SS];
    const int b = blockIdx.x;
    const int tid = threadIdx.x;

    cum[tid] = dur[b * SS + tid];
    // Hillis-Steele inclusive scan
    for (int off = 1; off < SS; off <<= 1) {
        __syncthreads();
        int v = (tid >= off) ? cum[tid - off] : 0;
        __syncthreads();
        cum[tid] += v;
    }
    __syncthreads();

    const int mel_len = cum[SS - 1];
    if (tid == 0) out[MEL_OFF + b] = (float)mel_len;

    for (int k = 0; k < MAXLEN / SS; ++k) {
        const int t = tid + k * SS;
        // searchsorted(cum, t, side='right'): first j with cum[j] > t
        int lo = 0, hi = SS;
        while (lo < hi) {
            int mid = (lo + hi) >> 1;
            if (cum[mid] <= t) lo = mid + 1; else hi = mid;
        }
        int idx = (lo < SS) ? lo : (SS - 1);
        idxbuf[b * MAXLEN + t] = (t < mel_len) ? idx : -1;
        out[MASK_OFF + b * MAXLEN + t] = mel_mask_in[b * MAXLEN + t] ? 1.0f : 0.0f;
    }
}

// Expansion: 24576 blocks x 256 thr x 4 float4 each = 25,165,824 float4.
// XCD swizzle: physical block L -> work W = (L%8)*(NB/8) + L/8 so each XCD
// (round-robin L%8) owns a contiguous 1/8 of the output; x-row reuse between
// adjacent frames then stays inside one XCD's L2.
// Nontemporal stores: out is write-once; keep L2 capacity for the x gathers.
#define NB_EXP 24576
__global__ __launch_bounds__(256) void k_expand(
    const vfloat4* __restrict__ x4,
    const int* __restrict__ idxbuf,
    vfloat4* __restrict__ out4)
{
    const int L = blockIdx.x;
    const int W = (L & 7) * (NB_EXP / 8) + (L >> 3);
    const int base = W * 1024 + (int)threadIdx.x;
#pragma unroll
    for (int j = 0; j < 4; ++j) {
        const int i = base + j * 256;          // flat float4 index, coalesced per iter
        const int ft = i / H4;                 // global frame index b*8192+t
        const int c  = i - ft * H4;
        const int id = idxbuf[ft];
        vfloat4 v = (vfloat4)(0.f);
        if (id >= 0) {
            const int b = ft >> 13;
            v = x4[(size_t)(b * SS + id) * H4 + c];
        }
        __builtin_nontemporal_store(v, &out4[i]);
    }
}

extern "C" void kernel_launch(void* const* d_in, const int* in_sizes, int n_in,
                              void* d_out, int out_size, void* d_ws, size_t ws_size,
                              hipStream_t stream) {
    // setup_inputs order: x, src_mask, mel_mask, duration_target, pitch_target, max_len
    const float* x = (const float*)d_in[0];
    const int* mel_mask_in = (const int*)d_in[2];
    const int* dur = (const int*)d_in[3];
    float* out = (float*)d_out;
    int* idxbuf = (int*)d_ws;   // BB*MAXLEN ints = 1 MB

    k_prep<<<BB, 1024, 0, stream>>>(dur, mel_mask_in, out, idxbuf);
    k_expand<<<NB_EXP, 256, 0, stream>>>((const vfloat4*)x, idxbuf, (vfloat4*)out);
}